// Round 16
// baseline (319.669 us; speedup 1.0000x reference)
//
#include <hip/hip_runtime.h>
#include <math.h>

#define HD   256
#define FIN  32
#define NP   8192
#define PGH  4096
#define NLVL 15
#define TN   16

typedef __attribute__((ext_vector_type(4))) short v4s;
typedef __attribute__((ext_vector_type(8))) short v8s;
typedef __attribute__((ext_vector_type(4))) float v4f;

#define MFMA __builtin_amdgcn_mfma_f32_16x16x32_bf16

// packed bf16 hi/lo fragment-layout weights (written by prep_kernel each launch)
__device__ __align__(16) unsigned short g_wpk[606208];

__device__ __forceinline__ float lrelu(float x) { return x > 0.f ? x : 0.1f * x; }

__device__ __forceinline__ void cvt_duo(float v, unsigned short& hi, unsigned short& lo) {
    unsigned int u = __float_as_uint(v);
    unsigned int r = u + 0x7fffu + ((u >> 16) & 1u);       // RNE to bf16
    hi = (unsigned short)(r >> 16);
    float d = v - __uint_as_float((unsigned int)hi << 16);
    unsigned int u2 = __float_as_uint(d);
    unsigned int r2 = u2 + 0x7fffu + ((u2 >> 16) & 1u);
    lo = (unsigned short)(r2 >> 16);
}

__device__ __forceinline__ v8s pack8(v4s a, v4s b) {
    v8s r; r[0]=a[0]; r[1]=a[1]; r[2]=a[2]; r[3]=a[3]; r[4]=b[0]; r[5]=b[1]; r[6]=b[2]; r[7]=b[3];
    return r;
}

// ---------------- prep: pack weights; inverse-mapped so WRITES are coalesced ----------------
__global__ __launch_bounds__(256) void prep_kernel(
    const float* __restrict__ gw1, const float* __restrict__ mw1,
    const float* __restrict__ gw2, const float* __restrict__ mw2,
    const float* __restrict__ glw2, const float* __restrict__ ow1)
{
    int t = blockIdx.x * 256 + threadIdx.x;
    const float* src; int base, N, idx;
    if (t < 36864)       { src = gw1;  base = 0;      N = 128; idx = t; }
    else if (t < 73728)  { src = mw1;  base = 73728;  N = 128; idx = t - 36864; }
    else if (t < 106496) { src = gw2;  base = 147456; N = 256; idx = t - 73728; }
    else if (t < 139264) { src = mw2;  base = 212992; N = 256; idx = t - 106496; }
    else if (t < 172032) { src = glw2; base = 278528; N = 256; idx = t - 139264; }
    else if (t < 303104) { src = ow1;  base = 344064; N = 256; idx = t - 172032; }
    else return;
    int nch = N >> 7;
    int s = idx >> 12, q = idx & 4095;
    int ct = q >> 9, r = q & 511, l = r >> 3, w = r & 7;
    int kk = (w & 3) | ((l >> 4) << 2) | ((w >> 2) << 4);
    int cc = ct * 16 + (l & 15);
    int ch = s & (nch - 1);
    int ks = (nch == 2) ? (s >> 1) : s;
    int col = ch * 128 + cc;
    int k = ks * 32 + kk;
    float v = src[k * N + col];
    unsigned short hi, lo; cvt_duo(v, hi, lo);
    g_wpk[base + s * 8192 + q] = hi;
    g_wpk[base + s * 8192 + 4096 + q] = lo;
}

// ---------------- pi kernel: prev_h = mlp(delay), + sdot epilogue (fp32) ----------------
__global__ __launch_bounds__(256) void pi_kernel(
    const float* __restrict__ delay,
    const float* __restrict__ w1, const float* __restrict__ b1,
    const float* __restrict__ w2, const float* __restrict__ b2,
    const float* __restrict__ av,
    float* __restrict__ outh, float* __restrict__ sdot)
{
    __shared__ float g1[TN][132];
    const int tid = threadIdx.x;
    const int node0 = blockIdx.x * TN;

    for (int t = tid; t < TN * 128; t += 256) {
        int i = t >> 7, jj = t & 127;
        g1[i][jj] = lrelu(delay[node0 + i] * w1[jj] + b1[jj]);
    }
    __syncthreads();

    const int j = (tid & 63) * 4;
    const int rg = (tid >> 6) * 4;
    float acc[4][4];
    float4 bv = *(const float4*)&b2[j];
#pragma unroll
    for (int ri = 0; ri < 4; ri++) { acc[ri][0] = bv.x; acc[ri][1] = bv.y; acc[ri][2] = bv.z; acc[ri][3] = bv.w; }

#pragma unroll 2
    for (int k = 0; k < 128; k += 4) {
        float4 x0 = *(const float4*)&g1[rg + 0][k];
        float4 x1 = *(const float4*)&g1[rg + 1][k];
        float4 x2v = *(const float4*)&g1[rg + 2][k];
        float4 x3 = *(const float4*)&g1[rg + 3][k];
        const float* wp = w2 + (size_t)k * 256 + j;
#define PIK(comp, off) { float4 wv = *(const float4*)(wp + (off) * 256); \
    acc[0][0] += x0.comp * wv.x; acc[0][1] += x0.comp * wv.y; acc[0][2] += x0.comp * wv.z; acc[0][3] += x0.comp * wv.w; \
    acc[1][0] += x1.comp * wv.x; acc[1][1] += x1.comp * wv.y; acc[1][2] += x1.comp * wv.z; acc[1][3] += x1.comp * wv.w; \
    acc[2][0] += x2v.comp * wv.x; acc[2][1] += x2v.comp * wv.y; acc[2][2] += x2v.comp * wv.z; acc[2][3] += x2v.comp * wv.w; \
    acc[3][0] += x3.comp * wv.x; acc[3][1] += x3.comp * wv.y; acc[3][2] += x3.comp * wv.z; acc[3][3] += x3.comp * wv.w; }
        PIK(x, 0) PIK(y, 1) PIK(z, 2) PIK(w, 3)
#undef PIK
    }
    float4 avj = *(const float4*)&av[64 + j];
#pragma unroll
    for (int ri = 0; ri < 4; ri++) {
        *(float4*)&outh[(node0 + rg + ri) * HD + j] =
            make_float4(acc[ri][0], acc[ri][1], acc[ri][2], acc[ri][3]);
        float p = acc[ri][0] * avj.x + acc[ri][1] * avj.y + acc[ri][2] * avj.z + acc[ri][3] * avj.w;
#pragma unroll
        for (int off = 1; off < 64; off <<= 1) p += __shfl_xor(p, off);
        if ((tid & 63) == 0) sdot[node0 + rg + ri] = p;
    }
}

// ---------------- per-level kernel: 512 threads; blocks 0..255 gate, 256..511 mod ----------------
__global__ __launch_bounds__(512, 4) void level_kernel(
    const float* __restrict__ prevh, float* __restrict__ nexth,
    const float* __restrict__ sdot_prev, float* __restrict__ sdot_next,
    const float* __restrict__ feat, const float* __restrict__ bitpos,
    const int* __restrict__ srcidx,
    const float* __restrict__ g_w1, const float* __restrict__ g_b1,
    const float* __restrict__ g_b2,
    const float* __restrict__ m_w1, const float* __restrict__ m_b1,
    const float* __restrict__ m_b2,
    const float* __restrict__ t_w1, const float* __restrict__ t_b1,
    const float* __restrict__ t_w2, const float* __restrict__ t_b2,
    const float* __restrict__ p_w1, const float* __restrict__ p_b1,
    const float* __restrict__ p_w2, const float* __restrict__ p_b2,
    const float* __restrict__ av,
    int level, int apply_relu)
{
    __shared__ unsigned short xh_lds[16 * 296];
    __shared__ unsigned short xl_lds[16 * 296];
    __shared__ unsigned short h1h_lds[16 * 136];
    __shared__ unsigned short h1l_lds[16 * 136];
    __shared__ int   src_lds[128];
    __shared__ float dstf_lds[16][32];
    __shared__ float ztt_lds[16][32];
    __shared__ float alpha_lds[128];
    __shared__ float xbp_lds[16];
    __shared__ float av_lds[64];
    __shared__ float tw2av_lds[32];
    __shared__ float pw2av_lds[32];
    __shared__ float bias_av[2];
    __shared__ float red_lds[16][8];

    const int tid = threadIdx.x;
    const bool is_gate = (blockIdx.x < 256);
    const int node0 = is_gate ? (blockIdx.x * TN) : (PGH + ((int)blockIdx.x - 256) * TN);

    const float* w1 = is_gate ? g_w1 : m_w1;
    const float* b1 = is_gate ? g_b1 : m_b1;
    const float* b2 = is_gate ? g_b2 : m_b2;
    const unsigned short* pk1 = g_wpk + (is_gate ? 0 : 73728);
    const unsigned short* pk2 = g_wpk + (is_gate ? 147456 : 212992);

    const int lane = tid & 63, wv = tid >> 6;
    const int lr = lane & 15, lg = lane >> 4;

    // --- early prefetch: GEMM1 B stages 0-1 (land during gather) ---
    const unsigned short* wb1p = pk1 + wv * 512 + lane * 8;
    v8s P1h0 = *(const v8s*)(wb1p);
    v8s P1l0 = *(const v8s*)(wb1p + 4096);
    v8s P1h1 = *(const v8s*)(wb1p + 8192);
    v8s P1l1 = *(const v8s*)(wb1p + 12288);

    // --- early scattered loads for mod logits (sv, bpv) ---
    float sv_r = 0.f, bpv_r = 0.f;
    if (!is_gate && tid < 256) {
        int i = tid >> 4, f = (tid >> 1) & 7;
        int si = srcidx[(level * NP + node0 + i) * 8 + f];
        sv_r = sdot_prev[si];
        bpv_r = bitpos[(level * NP + node0 + i) * 8 + f];
    }

    if (tid < 128) src_lds[tid] = srcidx[(level * NP + node0) * 8 + tid];

    if (is_gate) {
        {
            int i = tid >> 5, k = tid & 31;
            float v = feat[((level + 1) * NP + node0 + i) * FIN + k];
            unsigned short h, l; cvt_duo(v, h, l);
            xh_lds[i * 296 + 256 + k] = h; xl_lds[i * 296 + 256 + k] = l;
        }
        __syncthreads();   // src_lds visible
        // gather + per-channel softmax: thread = (channel-pair, node-quad), float2 loads
        {
            const int c2 = (tid & 127) * 2;
            const int nd0 = (tid >> 7) * 4;
            for (int s0 = 0; s0 < 4; s0 += 2) {
                const int sA = nd0 + s0, sB = sA + 1;
                const int* spA = &src_lds[sA * 8];
                const int* spB = &src_lds[sB * 8];
                float2 ma[8], mb[8];
#pragma unroll
                for (int f = 0; f < 8; f++) ma[f] = *(const float2*)&prevh[spA[f] * HD + c2];
#pragma unroll
                for (int f = 0; f < 8; f++) mb[f] = *(const float2*)&prevh[spB[f] * HD + c2];
                float mxa0 = -1e30f, mxa1 = -1e30f, mxb0 = -1e30f, mxb1 = -1e30f;
#pragma unroll
                for (int f = 0; f < 8; f++) {
                    mxa0 = fmaxf(mxa0, ma[f].x); mxa1 = fmaxf(mxa1, ma[f].y);
                    mxb0 = fmaxf(mxb0, mb[f].x); mxb1 = fmaxf(mxb1, mb[f].y);
                }
                float sa0 = 0.f, wa0 = 0.f, sa1 = 0.f, wa1 = 0.f;
                float sb0 = 0.f, wb0 = 0.f, sb1 = 0.f, wb1 = 0.f;
#pragma unroll
                for (int f = 0; f < 8; f++) {
                    float e0 = __expf(ma[f].x - mxa0); sa0 += e0; wa0 += ma[f].x * e0;
                    float e1 = __expf(ma[f].y - mxa1); sa1 += e1; wa1 += ma[f].y * e1;
                    float e2 = __expf(mb[f].x - mxb0); sb0 += e2; wb0 += mb[f].x * e2;
                    float e3 = __expf(mb[f].y - mxb1); sb1 += e3; wb1 += mb[f].y * e3;
                }
                unsigned short h0, l0, h1, l1;
                ushort2 th, tl;
                cvt_duo(wa0 / sa0, h0, l0); cvt_duo(wa1 / sa1, h1, l1);
                th.x = h0; th.y = h1; tl.x = l0; tl.y = l1;
                *(ushort2*)&xh_lds[sA * 296 + c2] = th;
                *(ushort2*)&xl_lds[sA * 296 + c2] = tl;
                cvt_duo(wb0 / sb0, h0, l0); cvt_duo(wb1 / sb1, h1, l1);
                th.x = h0; th.y = h1; tl.x = l0; tl.y = l1;
                *(ushort2*)&xh_lds[sB * 296 + c2] = th;
                *(ushort2*)&xl_lds[sB * 296 + c2] = tl;
            }
        }
        __syncthreads();
    } else {
        {
            int i = tid >> 5, k = tid & 31;
            float v = feat[((level + 1) * NP + node0 + i) * FIN + k];
            dstf_lds[i][k] = v;
            unsigned short h, l; cvt_duo(v, h, l);
            xh_lds[i * 296 + 257 + k] = h; xl_lds[i * 296 + 257 + k] = l;
        }
        if (tid < 64) av_lds[tid] = av[tid];
        __syncthreads();

        // ztt = lrelu(dstf @ t_w1 + t_b1)
        {
            int i = tid >> 5, jj = tid & 31;
            float a = t_b1[jj];
#pragma unroll 8
            for (int k = 0; k < 32; k++) a += dstf_lds[i][k] * t_w1[k * 32 + jj];
            ztt_lds[i][jj] = lrelu(a);
        }
        if (tid < 32) {
            float s = 0.f;
#pragma unroll 8
            for (int jj = 0; jj < 32; jj++) s += t_w2[tid * 32 + jj] * av_lds[jj];
            tw2av_lds[tid] = s;
        } else if (tid < 64) {
            int k = tid - 32;
            float s = 0.f;
#pragma unroll 8
            for (int jj = 0; jj < 32; jj++) s += p_w2[k * 32 + jj] * av_lds[32 + jj];
            pw2av_lds[k] = s;
        } else if (tid == 64) {
            float s = 0.f;
#pragma unroll 8
            for (int jj = 0; jj < 32; jj++) s += t_b2[jj] * av_lds[jj];
            bias_av[0] = s;
        } else if (tid == 65) {
            float s = 0.f;
#pragma unroll 8
            for (int jj = 0; jj < 32; jj++) s += p_b2[jj] * av_lds[32 + jj];
            bias_av[1] = s;
        }
        __syncthreads();

        // logits + softmax over fanin (sv/bpv pre-loaded at kernel entry)
        if (tid < 256) {
            const int jg = tid & 1, f = (tid >> 1) & 7, i = tid >> 4;
            const float bpv = bpv_r;
            float part = 0.f;
            const int k0 = jg * 16;
#pragma unroll
            for (int k = k0; k < k0 + 16; k++) {
                float h1pk = lrelu(bpv * p_w1[k] + p_b1[k]);
                part += h1pk * pw2av_lds[k];
                part += ztt_lds[i][k] * tw2av_lds[k];
            }
            part += __shfl_xor(part, 1);
            float logit = part + bias_av[0] + bias_av[1] + sv_r;
            float mx = logit;
            mx = fmaxf(mx, __shfl_xor(mx, 2));
            mx = fmaxf(mx, __shfl_xor(mx, 4));
            mx = fmaxf(mx, __shfl_xor(mx, 8));
            float e = __expf(logit - mx);
            float ssum = e;
            ssum += __shfl_xor(ssum, 2);
            ssum += __shfl_xor(ssum, 4);
            ssum += __shfl_xor(ssum, 8);
            float alpha = e / ssum;
            if (jg == 0) alpha_lds[i * 8 + f] = alpha;
            float ab = alpha * bpv;
            ab += __shfl_xor(ab, 2);
            ab += __shfl_xor(ab, 4);
            ab += __shfl_xor(ab, 8);
            if ((tid & 15) == 0) xbp_lds[i] = ab;
        }
        __syncthreads();

        // neigh_m: thread = (channel-pair, node-quad), float2 loads
        {
            const int c2 = (tid & 127) * 2;
            const int nd0 = (tid >> 7) * 4;
            for (int s0 = 0; s0 < 4; s0 += 2) {
                const int sA = nd0 + s0, sB = sA + 1;
                const int* spA = &src_lds[sA * 8];
                const int* spB = &src_lds[sB * 8];
                float2 ma[8], mb[8];
#pragma unroll
                for (int f = 0; f < 8; f++) ma[f] = *(const float2*)&prevh[spA[f] * HD + c2];
#pragma unroll
                for (int f = 0; f < 8; f++) mb[f] = *(const float2*)&prevh[spB[f] * HD + c2];
                const float* apA = &alpha_lds[sA * 8];
                const float* apB = &alpha_lds[sB * 8];
                float a0 = 0.f, a1 = 0.f, b0 = 0.f, b1v = 0.f;
#pragma unroll
                for (int f = 0; f < 8; f++) {
                    a0 += apA[f] * ma[f].x; a1 += apA[f] * ma[f].y;
                    b0 += apB[f] * mb[f].x; b1v += apB[f] * mb[f].y;
                }
                unsigned short h0, l0, h1, l1;
                ushort2 th, tl;
                cvt_duo(a0, h0, l0); cvt_duo(a1, h1, l1);
                th.x = h0; th.y = h1; tl.x = l0; tl.y = l1;
                *(ushort2*)&xh_lds[sA * 296 + c2] = th;
                *(ushort2*)&xl_lds[sA * 296 + c2] = tl;
                cvt_duo(b0, h0, l0); cvt_duo(b1v, h1, l1);
                th.x = h0; th.y = h1; tl.x = l0; tl.y = l1;
                *(ushort2*)&xh_lds[sB * 296 + c2] = th;
                *(ushort2*)&xl_lds[sB * 296 + c2] = tl;
            }
        }
        if (tid < TN) {
            unsigned short h, l; cvt_duo(xbp_lds[tid], h, l);
            xh_lds[tid * 296 + 256] = h; xl_lds[tid * 296 + 256] = l;
        }
        __syncthreads();
    }

    // ---------- GEMM1 (MFMA bf16x3): (16 x 288) @ (288 x 128); stages 0-1 prefetched ----------
    {
        const unsigned short* xrh = xh_lds + lr * 296 + 4 * lg;
        const unsigned short* xrl = xl_lds + lr * 296 + 4 * lg;
        const int colg = wv * 16 + lr;
        float bb = b1[colg];
        v4f acc = {bb, bb, bb, bb};
        {
            v8s Ah = pack8(*(const v4s*)(xrh), *(const v4s*)(xrh + 16));
            v8s Al = pack8(*(const v4s*)(xrl), *(const v4s*)(xrl + 16));
            acc = MFMA(Ah, P1h0, acc, 0, 0, 0);
            acc = MFMA(Ah, P1l0, acc, 0, 0, 0);
            acc = MFMA(Al, P1h0, acc, 0, 0, 0);
            v8s Ah1 = pack8(*(const v4s*)(xrh + 32), *(const v4s*)(xrh + 48));
            v8s Al1 = pack8(*(const v4s*)(xrl + 32), *(const v4s*)(xrl + 48));
            acc = MFMA(Ah1, P1h1, acc, 0, 0, 0);
            acc = MFMA(Ah1, P1l1, acc, 0, 0, 0);
            acc = MFMA(Al1, P1h1, acc, 0, 0, 0);
        }
#pragma unroll
        for (int s = 2; s < 9; ++s) {
            const unsigned short* wb = pk1 + s * 8192 + wv * 512 + lane * 8;
            v8s Bh = *(const v8s*)(wb);
            v8s Bl = *(const v8s*)(wb + 4096);
            int k0 = s * 32;
            v8s Ah = pack8(*(const v4s*)(xrh + k0), *(const v4s*)(xrh + k0 + 16));
            v8s Al = pack8(*(const v4s*)(xrl + k0), *(const v4s*)(xrl + k0 + 16));
            acc = MFMA(Ah, Bh, acc, 0, 0, 0);
            acc = MFMA(Ah, Bl, acc, 0, 0, 0);
            acc = MFMA(Al, Bh, acc, 0, 0, 0);
        }
        // prefetch GEMM2 stage (ks=0, both col chunks); lands during epilogue + barrier
        const unsigned short* wb2p = pk2 + wv * 512 + lane * 8;
        v8s P2h0 = *(const v8s*)(wb2p);
        v8s P2l0 = *(const v8s*)(wb2p + 4096);
        v8s P2h1 = *(const v8s*)(wb2p + 8192);
        v8s P2l1 = *(const v8s*)(wb2p + 12288);

        float w288 = is_gate ? 0.f : w1[288 * 128 + colg];
#pragma unroll
        for (int r = 0; r < 4; ++r) {
            int row = lg * 4 + r;
            float v = acc[r];
            if (!is_gate) v += dstf_lds[row][31] * w288;
            v = lrelu(v);
            unsigned short h, l; cvt_duo(v, h, l);
            h1h_lds[row * 136 + colg] = h;
            h1l_lds[row * 136 + colg] = l;
        }
        __syncthreads();

        // ---------- GEMM2 (MFMA bf16x3): (16 x 128) @ (128 x 256) + relu + sdot ----------
        const unsigned short* h1rh = h1h_lds + lr * 136 + 4 * lg;
        const unsigned short* h1rl = h1l_lds + lr * 136 + 4 * lg;
        const int col0 = wv * 16 + lr;
        float bb0 = b2[col0], bb1 = b2[128 + col0];
        v4f acc0 = {bb0, bb0, bb0, bb0};
        v4f acc1 = {bb1, bb1, bb1, bb1};
        {
            v8s Ah = pack8(*(const v4s*)(h1rh), *(const v4s*)(h1rh + 16));
            v8s Al = pack8(*(const v4s*)(h1rl), *(const v4s*)(h1rl + 16));
            acc0 = MFMA(Ah, P2h0, acc0, 0, 0, 0);
            acc0 = MFMA(Ah, P2l0, acc0, 0, 0, 0);
            acc0 = MFMA(Al, P2h0, acc0, 0, 0, 0);
            acc1 = MFMA(Ah, P2h1, acc1, 0, 0, 0);
            acc1 = MFMA(Ah, P2l1, acc1, 0, 0, 0);
            acc1 = MFMA(Al, P2h1, acc1, 0, 0, 0);
        }
#pragma unroll
        for (int ks = 1; ks < 4; ++ks) {
            int k0 = ks * 32;
            v8s Ah = pack8(*(const v4s*)(h1rh + k0), *(const v4s*)(h1rh + k0 + 16));
            v8s Al = pack8(*(const v4s*)(h1rl + k0), *(const v4s*)(h1rl + k0 + 16));
            const unsigned short* wb0 = pk2 + (ks * 2 + 0) * 8192 + wv * 512 + lane * 8;
            const unsigned short* wb1 = pk2 + (ks * 2 + 1) * 8192 + wv * 512 + lane * 8;
            v8s Bh0 = *(const v8s*)(wb0);
            v8s Bl0 = *(const v8s*)(wb0 + 4096);
            v8s Bh1 = *(const v8s*)(wb1);
            v8s Bl1 = *(const v8s*)(wb1 + 4096);
            acc0 = MFMA(Ah, Bh0, acc0, 0, 0, 0);
            acc0 = MFMA(Ah, Bl0, acc0, 0, 0, 0);
            acc0 = MFMA(Al, Bh0, acc0, 0, 0, 0);
            acc1 = MFMA(Ah, Bh1, acc1, 0, 0, 0);
            acc1 = MFMA(Ah, Bl1, acc1, 0, 0, 0);
            acc1 = MFMA(Al, Bh1, acc1, 0, 0, 0);
        }
        float pr[4] = {0.f, 0.f, 0.f, 0.f};
#pragma unroll
        for (int r = 0; r < 4; ++r) {
            int row = lg * 4 + r;
            float v = acc0[r];
            if (apply_relu) v = fmaxf(v, 0.f);
            nexth[(node0 + row) * HD + col0] = v;
            pr[r] += v * av[64 + col0];
            float v2 = acc1[r];
            if (apply_relu) v2 = fmaxf(v2, 0.f);
            nexth[(node0 + row) * HD + 128 + col0] = v2;
            pr[r] += v2 * av[192 + col0];
        }
#pragma unroll
        for (int off = 1; off < 16; off <<= 1) {
#pragma unroll
            for (int r = 0; r < 4; ++r) pr[r] += __shfl_xor(pr[r], off);
        }
        if (lr == 0) {
#pragma unroll
            for (int r = 0; r < 4; ++r) red_lds[lg * 4 + r][wv] = pr[r];
        }
        __syncthreads();
        if (tid < TN) {
            float s = 0.f;
#pragma unroll
            for (int w = 0; w < 8; w++) s += red_lds[tid][w];
            sdot_next[node0 + tid] = s;
        }
    }
}

// ---------------- final kernel: 512 threads; glob mlp + concat + out mlp (fused, MFMA) ----------------
__global__ __launch_bounds__(512, 4) void final_kernel(
    const float* __restrict__ prevh, const float* __restrict__ pofeat,
    const float* __restrict__ gl_w1, const float* __restrict__ gl_b1,
    const float* __restrict__ gl_b2,
    const float* __restrict__ o_b1,
    const float* __restrict__ o_w2, const float* __restrict__ o_b2,
    float* __restrict__ out)
{
    __shared__ unsigned short x2h[16 * 520];
    __shared__ unsigned short x2l[16 * 520];
    __shared__ unsigned short g1h[16 * 136];
    __shared__ unsigned short g1l[16 * 136];
    __shared__ float ow2_lds[256];
    __shared__ float red_lds[16][8];

    const int tid = threadIdx.x;
    const int node0 = blockIdx.x * TN;
    const unsigned short* pkG = g_wpk + 278528;
    const unsigned short* pkO = g_wpk + 344064;

    const int lane = tid & 63, wv = tid >> 6;
    const int lr = lane & 15, lg = lane >> 4;
    const int col0 = wv * 16 + lr;

    // early prefetch: glob stage ks=0, both col chunks
    const unsigned short* wbgp = pkG + wv * 512 + lane * 8;
    v8s PGh0 = *(const v8s*)(wbgp);
    v8s PGl0 = *(const v8s*)(wbgp + 4096);
    v8s PGh1 = *(const v8s*)(wbgp + 8192);
    v8s PGl1 = *(const v8s*)(wbgp + 12288);

    for (int q = tid; q < TN * 64; q += 512) {
        int i = q >> 6, c4 = (q & 63) * 4;
        float4 v = *(const float4*)&prevh[(node0 + i) * HD + c4];
        unsigned short h0, l0, h1, l1;
        ushort2 th, tl;
        cvt_duo(v.x, h0, l0); cvt_duo(v.y, h1, l1);
        th.x = h0; th.y = h1; tl.x = l0; tl.y = l1;
        *(ushort2*)&x2h[i * 520 + c4] = th;
        *(ushort2*)&x2l[i * 520 + c4] = tl;
        cvt_duo(v.z, h0, l0); cvt_duo(v.w, h1, l1);
        th.x = h0; th.y = h1; tl.x = l0; tl.y = l1;
        *(ushort2*)&x2h[i * 520 + c4 + 2] = th;
        *(ushort2*)&x2l[i * 520 + c4 + 2] = tl;
    }
    for (int t = tid; t < TN * 128; t += 512) {
        int i = t >> 7, jj = t & 127;
        float v = lrelu(pofeat[node0 + i] * gl_w1[jj] + gl_b1[jj]);
        unsigned short h, l; cvt_duo(v, h, l);
        g1h[i * 136 + jj] = h; g1l[i * 136 + jj] = l;
    }
    if (tid < 256) ow2_lds[tid] = o_w2[tid];
    __syncthreads();

    // glob layer 2 (MFMA): (16x128)@(128x256) -> x2 duo cols 256..511
    {
        const unsigned short* grh = g1h + lr * 136 + 4 * lg;
        const unsigned short* grl = g1l + lr * 136 + 4 * lg;
        float bb0 = gl_b2[col0], bb1 = gl_b2[128 + col0];
        v4f acc0 = {bb0, bb0, bb0, bb0};
        v4f acc1 = {bb1, bb1, bb1, bb1};
        {
            v8s Ah = pack8(*(const v4s*)(grh), *(const v4s*)(grh + 16));
            v8s Al = pack8(*(const v4s*)(grl), *(const v4s*)(grl + 16));
            acc0 = MFMA(Ah, PGh0, acc0, 0, 0, 0);
            acc0 = MFMA(Ah, PGl0, acc0, 0, 0, 0);
            acc0 = MFMA(Al, PGh0, acc0, 0, 0, 0);
            acc1 = MFMA(Ah, PGh1, acc1, 0, 0, 0);
            acc1 = MFMA(Ah, PGl1, acc1, 0, 0, 0);
            acc1 = MFMA(Al, PGh1, acc1, 0, 0, 0);
        }
#pragma unroll
        for (int ks = 1; ks < 4; ++ks) {
            int k0 = ks * 32;
            v8s Ah = pack8(*(const v4s*)(grh + k0), *(const v4s*)(grh + k0 + 16));
            v8s Al = pack8(*(const v4s*)(grl + k0), *(const v4s*)(grl + k0 + 16));
            const unsigned short* wb0 = pkG + (ks * 2 + 0) * 8192 + wv * 512 + lane * 8;
            const unsigned short* wb1 = pkG + (ks * 2 + 1) * 8192 + wv * 512 + lane * 8;
            v8s Bh0 = *(const v8s*)(wb0);
            v8s Bl0 = *(const v8s*)(wb0 + 4096);
            v8s Bh1 = *(const v8s*)(wb1);
            v8s Bl1 = *(const v8s*)(wb1 + 4096);
            acc0 = MFMA(Ah, Bh0, acc0, 0, 0, 0);
            acc0 = MFMA(Ah, Bl0, acc0, 0, 0, 0);
            acc0 = MFMA(Al, Bh0, acc0, 0, 0, 0);
            acc1 = MFMA(Ah, Bh1, acc1, 0, 0, 0);
            acc1 = MFMA(Ah, Bl1, acc1, 0, 0, 0);
            acc1 = MFMA(Al, Bh1, acc1, 0, 0, 0);
        }
        // prefetch out1 stage ks=0 (lands during epilogue + barrier)
        const unsigned short* wbop = pkO + wv * 512 + lane * 8;
        v8s POh0 = *(const v8s*)(wbop);
        v8s POl0 = *(const v8s*)(wbop + 4096);
        v8s POh1 = *(const v8s*)(wbop + 8192);
        v8s POl1 = *(const v8s*)(wbop + 12288);

#pragma unroll
        for (int r = 0; r < 4; ++r) {
            int row = lg * 4 + r;
            unsigned short h, l;
            cvt_duo(acc0[r], h, l); x2h[row * 520 + 256 + col0] = h; x2l[row * 520 + 256 + col0] = l;
            cvt_duo(acc1[r], h, l); x2h[row * 520 + 384 + col0] = h; x2l[row * 520 + 384 + col0] = l;
        }
        __syncthreads();

        // out layer 1 (MFMA, K=512, 16 K-stages x 2 col-chunks) fused with out layer 2
        const unsigned short* xrh = x2h + lr * 520 + 4 * lg;
        const unsigned short* xrl = x2l + lr * 520 + 4 * lg;
        float ob0 = o_b1[col0], ob1 = o_b1[128 + col0];
        v4f oacc0 = {ob0, ob0, ob0, ob0};
        v4f oacc1 = {ob1, ob1, ob1, ob1};
        {
            v8s Ah = pack8(*(const v4s*)(xrh), *(const v4s*)(xrh + 16));
            v8s Al = pack8(*(const v4s*)(xrl), *(const v4s*)(xrl + 16));
            oacc0 = MFMA(Ah, POh0, oacc0, 0, 0, 0);
            oacc0 = MFMA(Ah, POl0, oacc0, 0, 0, 0);
            oacc0 = MFMA(Al, POh0, oacc0, 0, 0, 0);
            oacc1 = MFMA(Ah, POh1, oacc1, 0, 0, 0);
            oacc1 = MFMA(Ah, POl1, oacc1, 0, 0, 0);
            oacc1 = MFMA(Al, POh1, oacc1, 0, 0, 0);
        }
        for (int ks = 1; ks < 16; ++ks) {
            int k0 = ks * 32;
            v8s Ah = pack8(*(const v4s*)(xrh + k0), *(const v4s*)(xrh + k0 + 16));
            v8s Al = pack8(*(const v4s*)(xrl + k0), *(const v4s*)(xrl + k0 + 16));
            const unsigned short* wb0 = pkO + (ks * 2 + 0) * 8192 + wv * 512 + lane * 8;
            const unsigned short* wb1 = pkO + (ks * 2 + 1) * 8192 + wv * 512 + lane * 8;
            v8s Bh0 = *(const v8s*)(wb0);
            v8s Bl0 = *(const v8s*)(wb0 + 4096);
            v8s Bh1 = *(const v8s*)(wb1);
            v8s Bl1 = *(const v8s*)(wb1 + 4096);
            oacc0 = MFMA(Ah, Bh0, oacc0, 0, 0, 0);
            oacc0 = MFMA(Ah, Bl0, oacc0, 0, 0, 0);
            oacc0 = MFMA(Al, Bh0, oacc0, 0, 0, 0);
            oacc1 = MFMA(Ah, Bh1, oacc1, 0, 0, 0);
            oacc1 = MFMA(Ah, Bl1, oacc1, 0, 0, 0);
            oacc1 = MFMA(Al, Bh1, oacc1, 0, 0, 0);
        }
        float pr[4] = {0.f, 0.f, 0.f, 0.f};
#pragma unroll
        for (int r = 0; r < 4; ++r) {
            pr[r] += lrelu(oacc0[r]) * ow2_lds[col0];
            pr[r] += lrelu(oacc1[r]) * ow2_lds[128 + col0];
        }
#pragma unroll
        for (int off = 1; off < 16; off <<= 1) {
#pragma unroll
            for (int r = 0; r < 4; ++r) pr[r] += __shfl_xor(pr[r], off);
        }
        if (lr == 0) {
#pragma unroll
            for (int r = 0; r < 4; ++r) red_lds[lg * 4 + r][wv] = pr[r];
        }
        __syncthreads();
        if (tid < TN) {
            float s = 0.f;
#pragma unroll
            for (int w = 0; w < 8; w++) s += red_lds[tid][w];
            out[node0 + tid] = s + o_b2[0];
        }
    }
}

extern "C" void kernel_launch(void* const* d_in, const int* in_sizes, int n_in,
                              void* d_out, int out_size, void* d_ws, size_t ws_size,
                              hipStream_t stream)
{
    const float* delay    = (const float*)d_in[0];
    const float* feat     = (const float*)d_in[1];
    const float* bitpos   = (const float*)d_in[2];
    const float* pofeat   = (const float*)d_in[3];
    const int*   srcidx   = (const int*)  d_in[4];
    const float* pi_w1    = (const float*)d_in[5];
    const float* pi_b1    = (const float*)d_in[6];
    const float* pi_w2    = (const float*)d_in[7];
    const float* pi_b2    = (const float*)d_in[8];
    const float* gate_w1  = (const float*)d_in[9];
    const float* gate_b1  = (const float*)d_in[10];
    const float* gate_w2  = (const float*)d_in[11];
    const float* gate_b2  = (const float*)d_in[12];
    const float* mod_w1   = (const float*)d_in[13];
    const float* mod_b1   = (const float*)d_in[14];
    const float* mod_w2   = (const float*)d_in[15];
    const float* mod_b2   = (const float*)d_in[16];
    const float* type_w1  = (const float*)d_in[17];
    const float* type_b1  = (const float*)d_in[18];
    const float* type_w2  = (const float*)d_in[19];
    const float* type_b2  = (const float*)d_in[20];
    const float* pos_w1   = (const float*)d_in[21];
    const float* pos_b1   = (const float*)d_in[22];
    const float* pos_w2   = (const float*)d_in[23];
    const float* pos_b2   = (const float*)d_in[24];
    const float* attn_vec = (const float*)d_in[25];
    const float* glob_w1  = (const float*)d_in[26];
    const float* glob_b1  = (const float*)d_in[27];
    const float* glob_w2  = (const float*)d_in[28];
    const float* glob_b2  = (const float*)d_in[29];
    const float* out_w1   = (const float*)d_in[30];
    const float* out_b1   = (const float*)d_in[31];
    const float* out_w2   = (const float*)d_in[32];
    const float* out_b2   = (const float*)d_in[33];

    float* buf0 = (float*)d_ws;
    float* buf1 = buf0 + (size_t)NP * HD;
    float* sd0  = buf1 + (size_t)NP * HD;
    float* sd1  = sd0 + NP;

    prep_kernel<<<1184, 256, 0, stream>>>(gate_w1, mod_w1, gate_w2, mod_w2, glob_w2, out_w1);

    pi_kernel<<<NP / TN, 256, 0, stream>>>(delay, pi_w1, pi_b1, pi_w2, pi_b2,
                                           attn_vec, buf0, sd0);

    for (int l = 0; l < NLVL; l++) {
        float* pv = (l & 1) ? buf1 : buf0;
        float* nx = (l & 1) ? buf0 : buf1;
        float* sp = (l & 1) ? sd1 : sd0;
        float* sn = (l & 1) ? sd0 : sd1;
        level_kernel<<<NP / TN, 512, 0, stream>>>(
            pv, nx, sp, sn, feat, bitpos, srcidx,
            gate_w1, gate_b1, gate_b2,
            mod_w1, mod_b1, mod_b2,
            type_w1, type_b1, type_w2, type_b2,
            pos_w1, pos_b1, pos_w2, pos_b2,
            attn_vec, l, (l != NLVL - 1) ? 1 : 0);
    }

    final_kernel<<<NP / TN, 512, 0, stream>>>(
        buf1, pofeat,
        glob_w1, glob_b1, glob_b2,
        out_b1, out_w2, out_b2,
        (float*)d_out);
}

// Round 17
// 305.843 us; speedup vs baseline: 1.0452x; 1.0452x over previous
//
#include <hip/hip_runtime.h>
#include <math.h>

#define HD   256
#define FIN  32
#define NP   8192
#define PGH  4096
#define NLVL 15
#define TN   16

typedef __attribute__((ext_vector_type(4))) short v4s;
typedef __attribute__((ext_vector_type(8))) short v8s;
typedef __attribute__((ext_vector_type(4))) float v4f;

#define MFMA __builtin_amdgcn_mfma_f32_16x16x32_bf16

// packed bf16 hi/lo fragment-layout weights (written by prep_kernel each launch)
__device__ __align__(16) unsigned short g_wpk[606208];

__device__ __forceinline__ float lrelu(float x) { return x > 0.f ? x : 0.1f * x; }

__device__ __forceinline__ void cvt_duo(float v, unsigned short& hi, unsigned short& lo) {
    unsigned int u = __float_as_uint(v);
    unsigned int r = u + 0x7fffu + ((u >> 16) & 1u);       // RNE to bf16
    hi = (unsigned short)(r >> 16);
    float d = v - __uint_as_float((unsigned int)hi << 16);
    unsigned int u2 = __float_as_uint(d);
    unsigned int r2 = u2 + 0x7fffu + ((u2 >> 16) & 1u);
    lo = (unsigned short)(r2 >> 16);
}

__device__ __forceinline__ v8s pack8(v4s a, v4s b) {
    v8s r; r[0]=a[0]; r[1]=a[1]; r[2]=a[2]; r[3]=a[3]; r[4]=b[0]; r[5]=b[1]; r[6]=b[2]; r[7]=b[3];
    return r;
}

// ---------------- prep: pack weights; inverse-mapped so WRITES are coalesced ----------------
__global__ __launch_bounds__(256) void prep_kernel(
    const float* __restrict__ gw1, const float* __restrict__ mw1,
    const float* __restrict__ gw2, const float* __restrict__ mw2,
    const float* __restrict__ glw2, const float* __restrict__ ow1)
{
    int t = blockIdx.x * 256 + threadIdx.x;
    const float* src; int base, N, idx;
    if (t < 36864)       { src = gw1;  base = 0;      N = 128; idx = t; }
    else if (t < 73728)  { src = mw1;  base = 73728;  N = 128; idx = t - 36864; }
    else if (t < 106496) { src = gw2;  base = 147456; N = 256; idx = t - 73728; }
    else if (t < 139264) { src = mw2;  base = 212992; N = 256; idx = t - 106496; }
    else if (t < 172032) { src = glw2; base = 278528; N = 256; idx = t - 139264; }
    else if (t < 303104) { src = ow1;  base = 344064; N = 256; idx = t - 172032; }
    else return;
    int nch = N >> 7;
    int s = idx >> 12, q = idx & 4095;
    int ct = q >> 9, r = q & 511, l = r >> 3, w = r & 7;
    int kk = (w & 3) | ((l >> 4) << 2) | ((w >> 2) << 4);
    int cc = ct * 16 + (l & 15);
    int ch = s & (nch - 1);
    int ks = (nch == 2) ? (s >> 1) : s;
    int col = ch * 128 + cc;
    int k = ks * 32 + kk;
    float v = src[k * N + col];
    unsigned short hi, lo; cvt_duo(v, hi, lo);
    g_wpk[base + s * 8192 + q] = hi;
    g_wpk[base + s * 8192 + 4096 + q] = lo;
}

// ---------------- pi kernel: prev_h = mlp(delay), + sdot epilogue (fp32) ----------------
__global__ __launch_bounds__(256) void pi_kernel(
    const float* __restrict__ delay,
    const float* __restrict__ w1, const float* __restrict__ b1,
    const float* __restrict__ w2, const float* __restrict__ b2,
    const float* __restrict__ av,
    float* __restrict__ outh, float* __restrict__ sdot)
{
    __shared__ float g1[TN][132];
    const int tid = threadIdx.x;
    const int node0 = blockIdx.x * TN;

    for (int t = tid; t < TN * 128; t += 256) {
        int i = t >> 7, jj = t & 127;
        g1[i][jj] = lrelu(delay[node0 + i] * w1[jj] + b1[jj]);
    }
    __syncthreads();

    const int j = (tid & 63) * 4;
    const int rg = (tid >> 6) * 4;
    float acc[4][4];
    float4 bv = *(const float4*)&b2[j];
#pragma unroll
    for (int ri = 0; ri < 4; ri++) { acc[ri][0] = bv.x; acc[ri][1] = bv.y; acc[ri][2] = bv.z; acc[ri][3] = bv.w; }

#pragma unroll 2
    for (int k = 0; k < 128; k += 4) {
        float4 x0 = *(const float4*)&g1[rg + 0][k];
        float4 x1 = *(const float4*)&g1[rg + 1][k];
        float4 x2v = *(const float4*)&g1[rg + 2][k];
        float4 x3 = *(const float4*)&g1[rg + 3][k];
        const float* wp = w2 + (size_t)k * 256 + j;
#define PIK(comp, off) { float4 wv = *(const float4*)(wp + (off) * 256); \
    acc[0][0] += x0.comp * wv.x; acc[0][1] += x0.comp * wv.y; acc[0][2] += x0.comp * wv.z; acc[0][3] += x0.comp * wv.w; \
    acc[1][0] += x1.comp * wv.x; acc[1][1] += x1.comp * wv.y; acc[1][2] += x1.comp * wv.z; acc[1][3] += x1.comp * wv.w; \
    acc[2][0] += x2v.comp * wv.x; acc[2][1] += x2v.comp * wv.y; acc[2][2] += x2v.comp * wv.z; acc[2][3] += x2v.comp * wv.w; \
    acc[3][0] += x3.comp * wv.x; acc[3][1] += x3.comp * wv.y; acc[3][2] += x3.comp * wv.z; acc[3][3] += x3.comp * wv.w; }
        PIK(x, 0) PIK(y, 1) PIK(z, 2) PIK(w, 3)
#undef PIK
    }
    float4 avj = *(const float4*)&av[64 + j];
#pragma unroll
    for (int ri = 0; ri < 4; ri++) {
        *(float4*)&outh[(node0 + rg + ri) * HD + j] =
            make_float4(acc[ri][0], acc[ri][1], acc[ri][2], acc[ri][3]);
        float p = acc[ri][0] * avj.x + acc[ri][1] * avj.y + acc[ri][2] * avj.z + acc[ri][3] * avj.w;
#pragma unroll
        for (int off = 1; off < 64; off <<= 1) p += __shfl_xor(p, off);
        if ((tid & 63) == 0) sdot[node0 + rg + ri] = p;
    }
}

// ---------------- per-level kernel: 512 threads; blocks 0..255 gate, 256..511 mod ----------------
__global__ __launch_bounds__(512, 4) void level_kernel(
    const float* __restrict__ prevh, float* __restrict__ nexth,
    const float* __restrict__ sdot_prev, float* __restrict__ sdot_next,
    const float* __restrict__ feat, const float* __restrict__ bitpos,
    const int* __restrict__ srcidx,
    const float* __restrict__ g_w1, const float* __restrict__ g_b1,
    const float* __restrict__ g_b2,
    const float* __restrict__ m_w1, const float* __restrict__ m_b1,
    const float* __restrict__ m_b2,
    const float* __restrict__ t_w1, const float* __restrict__ t_b1,
    const float* __restrict__ t_w2, const float* __restrict__ t_b2,
    const float* __restrict__ p_w1, const float* __restrict__ p_b1,
    const float* __restrict__ p_w2, const float* __restrict__ p_b2,
    const float* __restrict__ av,
    int level, int apply_relu)
{
    __shared__ unsigned short xh_lds[16 * 296];
    __shared__ unsigned short xl_lds[16 * 296];
    __shared__ unsigned short h1h_lds[16 * 136];
    __shared__ unsigned short h1l_lds[16 * 136];
    __shared__ int   src_lds[128];
    __shared__ float dstf_lds[16][32];
    __shared__ float ztt_lds[16][32];
    __shared__ float alpha_lds[128];
    __shared__ float xbp_lds[16];
    __shared__ float av_lds[64];
    __shared__ float tw2av_lds[32];
    __shared__ float pw2av_lds[32];
    __shared__ float bias_av[2];
    __shared__ float red_lds[16][8];

    const int tid = threadIdx.x;
    const bool is_gate = (blockIdx.x < 256);
    const int node0 = is_gate ? (blockIdx.x * TN) : (PGH + ((int)blockIdx.x - 256) * TN);

    const float* w1 = is_gate ? g_w1 : m_w1;
    const float* b1 = is_gate ? g_b1 : m_b1;
    const float* b2 = is_gate ? g_b2 : m_b2;
    const unsigned short* pk1 = g_wpk + (is_gate ? 0 : 73728);
    const unsigned short* pk2 = g_wpk + (is_gate ? 147456 : 212992);

    const int lane = tid & 63, wv = tid >> 6;
    const int lr = lane & 15, lg = lane >> 4;

    // --- early prefetch: GEMM1 B stages 0-1 (land during gather) ---
    const unsigned short* wb1p = pk1 + wv * 512 + lane * 8;
    v8s P1h0 = *(const v8s*)(wb1p);
    v8s P1l0 = *(const v8s*)(wb1p + 4096);
    v8s P1h1 = *(const v8s*)(wb1p + 8192);
    v8s P1l1 = *(const v8s*)(wb1p + 12288);

    // --- early scattered loads for mod logits (sv, bpv) ---
    float sv_r = 0.f, bpv_r = 0.f;
    if (!is_gate && tid < 256) {
        int i = tid >> 4, f = (tid >> 1) & 7;
        int si = srcidx[(level * NP + node0 + i) * 8 + f];
        sv_r = sdot_prev[si];
        bpv_r = bitpos[(level * NP + node0 + i) * 8 + f];
    }

    if (tid < 128) src_lds[tid] = srcidx[(level * NP + node0) * 8 + tid];

    if (is_gate) {
        {
            int i = tid >> 5, k = tid & 31;
            float v = feat[((level + 1) * NP + node0 + i) * FIN + k];
            unsigned short h, l; cvt_duo(v, h, l);
            xh_lds[i * 296 + 256 + k] = h; xl_lds[i * 296 + 256 + k] = l;
        }
        __syncthreads();   // src_lds visible
        // gather + per-channel softmax: thread = (half, channel), 4-node chunks
        {
            const int c = tid & 255, sh = (tid >> 8) * 8;
            for (int s0 = 0; s0 < 8; s0 += 4) {
                const int* spA = &src_lds[(sh + s0 + 0) * 8];
                const int* spB = &src_lds[(sh + s0 + 1) * 8];
                const int* spC = &src_lds[(sh + s0 + 2) * 8];
                const int* spD = &src_lds[(sh + s0 + 3) * 8];
                float ma[8], mb[8], mc[8], md[8];
#pragma unroll
                for (int f = 0; f < 8; f++) ma[f] = prevh[spA[f] * HD + c];
#pragma unroll
                for (int f = 0; f < 8; f++) mb[f] = prevh[spB[f] * HD + c];
#pragma unroll
                for (int f = 0; f < 8; f++) mc[f] = prevh[spC[f] * HD + c];
#pragma unroll
                for (int f = 0; f < 8; f++) md[f] = prevh[spD[f] * HD + c];
                float mxa = -1e30f, mxb = -1e30f, mxc = -1e30f, mxd = -1e30f;
#pragma unroll
                for (int f = 0; f < 8; f++) {
                    mxa = fmaxf(mxa, ma[f]); mxb = fmaxf(mxb, mb[f]);
                    mxc = fmaxf(mxc, mc[f]); mxd = fmaxf(mxd, md[f]);
                }
                float sa = 0.f, wsa = 0.f, sb = 0.f, wsb = 0.f;
                float sc = 0.f, wsc = 0.f, sd = 0.f, wsd = 0.f;
#pragma unroll
                for (int f = 0; f < 8; f++) {
                    float ea = __expf(ma[f] - mxa); sa += ea; wsa += ma[f] * ea;
                    float eb = __expf(mb[f] - mxb); sb += eb; wsb += mb[f] * eb;
                    float ec = __expf(mc[f] - mxc); sc += ec; wsc += mc[f] * ec;
                    float ed = __expf(md[f] - mxd); sd += ed; wsd += md[f] * ed;
                }
                unsigned short h, l;
                cvt_duo(wsa / sa, h, l); xh_lds[(sh+s0+0)*296 + c] = h; xl_lds[(sh+s0+0)*296 + c] = l;
                cvt_duo(wsb / sb, h, l); xh_lds[(sh+s0+1)*296 + c] = h; xl_lds[(sh+s0+1)*296 + c] = l;
                cvt_duo(wsc / sc, h, l); xh_lds[(sh+s0+2)*296 + c] = h; xl_lds[(sh+s0+2)*296 + c] = l;
                cvt_duo(wsd / sd, h, l); xh_lds[(sh+s0+3)*296 + c] = h; xl_lds[(sh+s0+3)*296 + c] = l;
            }
        }
        __syncthreads();
    } else {
        {
            int i = tid >> 5, k = tid & 31;
            float v = feat[((level + 1) * NP + node0 + i) * FIN + k];
            dstf_lds[i][k] = v;
            unsigned short h, l; cvt_duo(v, h, l);
            xh_lds[i * 296 + 257 + k] = h; xl_lds[i * 296 + 257 + k] = l;
        }
        if (tid < 64) av_lds[tid] = av[tid];
        __syncthreads();

        // ztt = lrelu(dstf @ t_w1 + t_b1)
        {
            int i = tid >> 5, jj = tid & 31;
            float a = t_b1[jj];
#pragma unroll 8
            for (int k = 0; k < 32; k++) a += dstf_lds[i][k] * t_w1[k * 32 + jj];
            ztt_lds[i][jj] = lrelu(a);
        }
        if (tid < 32) {
            float s = 0.f;
#pragma unroll 8
            for (int jj = 0; jj < 32; jj++) s += t_w2[tid * 32 + jj] * av_lds[jj];
            tw2av_lds[tid] = s;
        } else if (tid < 64) {
            int k = tid - 32;
            float s = 0.f;
#pragma unroll 8
            for (int jj = 0; jj < 32; jj++) s += p_w2[k * 32 + jj] * av_lds[32 + jj];
            pw2av_lds[k] = s;
        } else if (tid == 64) {
            float s = 0.f;
#pragma unroll 8
            for (int jj = 0; jj < 32; jj++) s += t_b2[jj] * av_lds[jj];
            bias_av[0] = s;
        } else if (tid == 65) {
            float s = 0.f;
#pragma unroll 8
            for (int jj = 0; jj < 32; jj++) s += p_b2[jj] * av_lds[32 + jj];
            bias_av[1] = s;
        }
        __syncthreads();

        // logits + softmax over fanin (sv/bpv pre-loaded at kernel entry)
        if (tid < 256) {
            const int jg = tid & 1, f = (tid >> 1) & 7, i = tid >> 4;
            const float bpv = bpv_r;
            float part = 0.f;
            const int k0 = jg * 16;
#pragma unroll
            for (int k = k0; k < k0 + 16; k++) {
                float h1pk = lrelu(bpv * p_w1[k] + p_b1[k]);
                part += h1pk * pw2av_lds[k];
                part += ztt_lds[i][k] * tw2av_lds[k];
            }
            part += __shfl_xor(part, 1);
            float logit = part + bias_av[0] + bias_av[1] + sv_r;
            float mx = logit;
            mx = fmaxf(mx, __shfl_xor(mx, 2));
            mx = fmaxf(mx, __shfl_xor(mx, 4));
            mx = fmaxf(mx, __shfl_xor(mx, 8));
            float e = __expf(logit - mx);
            float ssum = e;
            ssum += __shfl_xor(ssum, 2);
            ssum += __shfl_xor(ssum, 4);
            ssum += __shfl_xor(ssum, 8);
            float alpha = e / ssum;
            if (jg == 0) alpha_lds[i * 8 + f] = alpha;
            float ab = alpha * bpv;
            ab += __shfl_xor(ab, 2);
            ab += __shfl_xor(ab, 4);
            ab += __shfl_xor(ab, 8);
            if ((tid & 15) == 0) xbp_lds[i] = ab;
        }
        __syncthreads();

        // neigh_m: thread = (half, channel), 4-node chunks; write x duo
        {
            const int c = tid & 255, sh = (tid >> 8) * 8;
            for (int s0 = 0; s0 < 8; s0 += 4) {
                const int* spA = &src_lds[(sh + s0 + 0) * 8];
                const int* spB = &src_lds[(sh + s0 + 1) * 8];
                const int* spC = &src_lds[(sh + s0 + 2) * 8];
                const int* spD = &src_lds[(sh + s0 + 3) * 8];
                float ma[8], mb[8], mc[8], md[8];
#pragma unroll
                for (int f = 0; f < 8; f++) ma[f] = prevh[spA[f] * HD + c];
#pragma unroll
                for (int f = 0; f < 8; f++) mb[f] = prevh[spB[f] * HD + c];
#pragma unroll
                for (int f = 0; f < 8; f++) mc[f] = prevh[spC[f] * HD + c];
#pragma unroll
                for (int f = 0; f < 8; f++) md[f] = prevh[spD[f] * HD + c];
                const float* apA = &alpha_lds[(sh + s0 + 0) * 8];
                const float* apB = &alpha_lds[(sh + s0 + 1) * 8];
                const float* apC = &alpha_lds[(sh + s0 + 2) * 8];
                const float* apD = &alpha_lds[(sh + s0 + 3) * 8];
                float aa = 0.f, ab2 = 0.f, ac = 0.f, ad = 0.f;
#pragma unroll
                for (int f = 0; f < 8; f++) {
                    aa  += apA[f] * ma[f]; ab2 += apB[f] * mb[f];
                    ac  += apC[f] * mc[f]; ad  += apD[f] * md[f];
                }
                unsigned short h, l;
                cvt_duo(aa,  h, l); xh_lds[(sh+s0+0)*296 + c] = h; xl_lds[(sh+s0+0)*296 + c] = l;
                cvt_duo(ab2, h, l); xh_lds[(sh+s0+1)*296 + c] = h; xl_lds[(sh+s0+1)*296 + c] = l;
                cvt_duo(ac,  h, l); xh_lds[(sh+s0+2)*296 + c] = h; xl_lds[(sh+s0+2)*296 + c] = l;
                cvt_duo(ad,  h, l); xh_lds[(sh+s0+3)*296 + c] = h; xl_lds[(sh+s0+3)*296 + c] = l;
            }
        }
        if (tid < TN) {
            unsigned short h, l; cvt_duo(xbp_lds[tid], h, l);
            xh_lds[tid * 296 + 256] = h; xl_lds[tid * 296 + 256] = l;
        }
        __syncthreads();
    }

    // ---------- GEMM1 (MFMA bf16x3): (16 x 288) @ (288 x 128); stages 0-1 prefetched ----------
    {
        const unsigned short* xrh = xh_lds + lr * 296 + 4 * lg;
        const unsigned short* xrl = xl_lds + lr * 296 + 4 * lg;
        const int colg = wv * 16 + lr;
        float bb = b1[colg];
        v4f acc = {bb, bb, bb, bb};
        {
            v8s Ah = pack8(*(const v4s*)(xrh), *(const v4s*)(xrh + 16));
            v8s Al = pack8(*(const v4s*)(xrl), *(const v4s*)(xrl + 16));
            acc = MFMA(Ah, P1h0, acc, 0, 0, 0);
            acc = MFMA(Ah, P1l0, acc, 0, 0, 0);
            acc = MFMA(Al, P1h0, acc, 0, 0, 0);
            v8s Ah1 = pack8(*(const v4s*)(xrh + 32), *(const v4s*)(xrh + 48));
            v8s Al1 = pack8(*(const v4s*)(xrl + 32), *(const v4s*)(xrl + 48));
            acc = MFMA(Ah1, P1h1, acc, 0, 0, 0);
            acc = MFMA(Ah1, P1l1, acc, 0, 0, 0);
            acc = MFMA(Al1, P1h1, acc, 0, 0, 0);
        }
#pragma unroll
        for (int s = 2; s < 9; ++s) {
            const unsigned short* wb = pk1 + s * 8192 + wv * 512 + lane * 8;
            v8s Bh = *(const v8s*)(wb);
            v8s Bl = *(const v8s*)(wb + 4096);
            int k0 = s * 32;
            v8s Ah = pack8(*(const v4s*)(xrh + k0), *(const v4s*)(xrh + k0 + 16));
            v8s Al = pack8(*(const v4s*)(xrl + k0), *(const v4s*)(xrl + k0 + 16));
            acc = MFMA(Ah, Bh, acc, 0, 0, 0);
            acc = MFMA(Ah, Bl, acc, 0, 0, 0);
            acc = MFMA(Al, Bh, acc, 0, 0, 0);
        }
        // prefetch GEMM2 stage (ks=0, both col chunks); lands during epilogue + barrier
        const unsigned short* wb2p = pk2 + wv * 512 + lane * 8;
        v8s P2h0 = *(const v8s*)(wb2p);
        v8s P2l0 = *(const v8s*)(wb2p + 4096);
        v8s P2h1 = *(const v8s*)(wb2p + 8192);
        v8s P2l1 = *(const v8s*)(wb2p + 12288);

        float w288 = is_gate ? 0.f : w1[288 * 128 + colg];
#pragma unroll
        for (int r = 0; r < 4; ++r) {
            int row = lg * 4 + r;
            float v = acc[r];
            if (!is_gate) v += dstf_lds[row][31] * w288;
            v = lrelu(v);
            unsigned short h, l; cvt_duo(v, h, l);
            h1h_lds[row * 136 + colg] = h;
            h1l_lds[row * 136 + colg] = l;
        }
        __syncthreads();

        // ---------- GEMM2 (MFMA bf16x3): (16 x 128) @ (128 x 256) + relu + sdot ----------
        const unsigned short* h1rh = h1h_lds + lr * 136 + 4 * lg;
        const unsigned short* h1rl = h1l_lds + lr * 136 + 4 * lg;
        const int col0 = wv * 16 + lr;
        float bb0 = b2[col0], bb1 = b2[128 + col0];
        v4f acc0 = {bb0, bb0, bb0, bb0};
        v4f acc1 = {bb1, bb1, bb1, bb1};
        {
            v8s Ah = pack8(*(const v4s*)(h1rh), *(const v4s*)(h1rh + 16));
            v8s Al = pack8(*(const v4s*)(h1rl), *(const v4s*)(h1rl + 16));
            acc0 = MFMA(Ah, P2h0, acc0, 0, 0, 0);
            acc0 = MFMA(Ah, P2l0, acc0, 0, 0, 0);
            acc0 = MFMA(Al, P2h0, acc0, 0, 0, 0);
            acc1 = MFMA(Ah, P2h1, acc1, 0, 0, 0);
            acc1 = MFMA(Ah, P2l1, acc1, 0, 0, 0);
            acc1 = MFMA(Al, P2h1, acc1, 0, 0, 0);
        }
#pragma unroll
        for (int ks = 1; ks < 4; ++ks) {
            int k0 = ks * 32;
            v8s Ah = pack8(*(const v4s*)(h1rh + k0), *(const v4s*)(h1rh + k0 + 16));
            v8s Al = pack8(*(const v4s*)(h1rl + k0), *(const v4s*)(h1rl + k0 + 16));
            const unsigned short* wb0 = pk2 + (ks * 2 + 0) * 8192 + wv * 512 + lane * 8;
            const unsigned short* wb1 = pk2 + (ks * 2 + 1) * 8192 + wv * 512 + lane * 8;
            v8s Bh0 = *(const v8s*)(wb0);
            v8s Bl0 = *(const v8s*)(wb0 + 4096);
            v8s Bh1 = *(const v8s*)(wb1);
            v8s Bl1 = *(const v8s*)(wb1 + 4096);
            acc0 = MFMA(Ah, Bh0, acc0, 0, 0, 0);
            acc0 = MFMA(Ah, Bl0, acc0, 0, 0, 0);
            acc0 = MFMA(Al, Bh0, acc0, 0, 0, 0);
            acc1 = MFMA(Ah, Bh1, acc1, 0, 0, 0);
            acc1 = MFMA(Ah, Bl1, acc1, 0, 0, 0);
            acc1 = MFMA(Al, Bh1, acc1, 0, 0, 0);
        }
        float pr[4] = {0.f, 0.f, 0.f, 0.f};
#pragma unroll
        for (int r = 0; r < 4; ++r) {
            int row = lg * 4 + r;
            float v = acc0[r];
            if (apply_relu) v = fmaxf(v, 0.f);
            nexth[(node0 + row) * HD + col0] = v;
            pr[r] += v * av[64 + col0];
            float v2 = acc1[r];
            if (apply_relu) v2 = fmaxf(v2, 0.f);
            nexth[(node0 + row) * HD + 128 + col0] = v2;
            pr[r] += v2 * av[192 + col0];
        }
#pragma unroll
        for (int off = 1; off < 16; off <<= 1) {
#pragma unroll
            for (int r = 0; r < 4; ++r) pr[r] += __shfl_xor(pr[r], off);
        }
        if (lr == 0) {
#pragma unroll
            for (int r = 0; r < 4; ++r) red_lds[lg * 4 + r][wv] = pr[r];
        }
        __syncthreads();
        if (tid < TN) {
            float s = 0.f;
#pragma unroll
            for (int w = 0; w < 8; w++) s += red_lds[tid][w];
            sdot_next[node0 + tid] = s;
        }
    }
}

// ---------------- final kernel: 512 threads; glob mlp + concat + out mlp (fused, MFMA) ----------------
__global__ __launch_bounds__(512, 4) void final_kernel(
    const float* __restrict__ prevh, const float* __restrict__ pofeat,
    const float* __restrict__ gl_w1, const float* __restrict__ gl_b1,
    const float* __restrict__ gl_b2,
    const float* __restrict__ o_b1,
    const float* __restrict__ o_w2, const float* __restrict__ o_b2,
    float* __restrict__ out)
{
    __shared__ unsigned short x2h[16 * 520];
    __shared__ unsigned short x2l[16 * 520];
    __shared__ unsigned short g1h[16 * 136];
    __shared__ unsigned short g1l[16 * 136];
    __shared__ float ow2_lds[256];
    __shared__ float red_lds[16][8];

    const int tid = threadIdx.x;
    const int node0 = blockIdx.x * TN;
    const unsigned short* pkG = g_wpk + 278528;
    const unsigned short* pkO = g_wpk + 344064;

    const int lane = tid & 63, wv = tid >> 6;
    const int lr = lane & 15, lg = lane >> 4;
    const int col0 = wv * 16 + lr;

    // early prefetch: glob stage ks=0, both col chunks
    const unsigned short* wbgp = pkG + wv * 512 + lane * 8;
    v8s PGh0 = *(const v8s*)(wbgp);
    v8s PGl0 = *(const v8s*)(wbgp + 4096);
    v8s PGh1 = *(const v8s*)(wbgp + 8192);
    v8s PGl1 = *(const v8s*)(wbgp + 12288);

    for (int q = tid; q < TN * 64; q += 512) {
        int i = q >> 6, c4 = (q & 63) * 4;
        float4 v = *(const float4*)&prevh[(node0 + i) * HD + c4];
        unsigned short h, l;
        cvt_duo(v.x, h, l); x2h[i * 520 + c4 + 0] = h; x2l[i * 520 + c4 + 0] = l;
        cvt_duo(v.y, h, l); x2h[i * 520 + c4 + 1] = h; x2l[i * 520 + c4 + 1] = l;
        cvt_duo(v.z, h, l); x2h[i * 520 + c4 + 2] = h; x2l[i * 520 + c4 + 2] = l;
        cvt_duo(v.w, h, l); x2h[i * 520 + c4 + 3] = h; x2l[i * 520 + c4 + 3] = l;
    }
    for (int t = tid; t < TN * 128; t += 512) {
        int i = t >> 7, jj = t & 127;
        float v = lrelu(pofeat[node0 + i] * gl_w1[jj] + gl_b1[jj]);
        unsigned short h, l; cvt_duo(v, h, l);
        g1h[i * 136 + jj] = h; g1l[i * 136 + jj] = l;
    }
    if (tid < 256) ow2_lds[tid] = o_w2[tid];
    __syncthreads();

    // glob layer 2 (MFMA): (16x128)@(128x256) -> x2 duo cols 256..511
    {
        const unsigned short* grh = g1h + lr * 136 + 4 * lg;
        const unsigned short* grl = g1l + lr * 136 + 4 * lg;
        float bb0 = gl_b2[col0], bb1 = gl_b2[128 + col0];
        v4f acc0 = {bb0, bb0, bb0, bb0};
        v4f acc1 = {bb1, bb1, bb1, bb1};
        {
            v8s Ah = pack8(*(const v4s*)(grh), *(const v4s*)(grh + 16));
            v8s Al = pack8(*(const v4s*)(grl), *(const v4s*)(grl + 16));
            acc0 = MFMA(Ah, PGh0, acc0, 0, 0, 0);
            acc0 = MFMA(Ah, PGl0, acc0, 0, 0, 0);
            acc0 = MFMA(Al, PGh0, acc0, 0, 0, 0);
            acc1 = MFMA(Ah, PGh1, acc1, 0, 0, 0);
            acc1 = MFMA(Ah, PGl1, acc1, 0, 0, 0);
            acc1 = MFMA(Al, PGh1, acc1, 0, 0, 0);
        }
#pragma unroll
        for (int ks = 1; ks < 4; ++ks) {
            int k0 = ks * 32;
            v8s Ah = pack8(*(const v4s*)(grh + k0), *(const v4s*)(grh + k0 + 16));
            v8s Al = pack8(*(const v4s*)(grl + k0), *(const v4s*)(grl + k0 + 16));
            const unsigned short* wb0 = pkG + (ks * 2 + 0) * 8192 + wv * 512 + lane * 8;
            const unsigned short* wb1 = pkG + (ks * 2 + 1) * 8192 + wv * 512 + lane * 8;
            v8s Bh0 = *(const v8s*)(wb0);
            v8s Bl0 = *(const v8s*)(wb0 + 4096);
            v8s Bh1 = *(const v8s*)(wb1);
            v8s Bl1 = *(const v8s*)(wb1 + 4096);
            acc0 = MFMA(Ah, Bh0, acc0, 0, 0, 0);
            acc0 = MFMA(Ah, Bl0, acc0, 0, 0, 0);
            acc0 = MFMA(Al, Bh0, acc0, 0, 0, 0);
            acc1 = MFMA(Ah, Bh1, acc1, 0, 0, 0);
            acc1 = MFMA(Ah, Bl1, acc1, 0, 0, 0);
            acc1 = MFMA(Al, Bh1, acc1, 0, 0, 0);
        }
        // prefetch out1 stage ks=0 (lands during epilogue + barrier)
        const unsigned short* wbop = pkO + wv * 512 + lane * 8;
        v8s POh0 = *(const v8s*)(wbop);
        v8s POl0 = *(const v8s*)(wbop + 4096);
        v8s POh1 = *(const v8s*)(wbop + 8192);
        v8s POl1 = *(const v8s*)(wbop + 12288);

#pragma unroll
        for (int r = 0; r < 4; ++r) {
            int row = lg * 4 + r;
            unsigned short h, l;
            cvt_duo(acc0[r], h, l); x2h[row * 520 + 256 + col0] = h; x2l[row * 520 + 256 + col0] = l;
            cvt_duo(acc1[r], h, l); x2h[row * 520 + 384 + col0] = h; x2l[row * 520 + 384 + col0] = l;
        }
        __syncthreads();

        // out layer 1 (MFMA, K=512, 16 K-stages x 2 col-chunks) fused with out layer 2
        const unsigned short* xrh = x2h + lr * 520 + 4 * lg;
        const unsigned short* xrl = x2l + lr * 520 + 4 * lg;
        float ob0 = o_b1[col0], ob1 = o_b1[128 + col0];
        v4f oacc0 = {ob0, ob0, ob0, ob0};
        v4f oacc1 = {ob1, ob1, ob1, ob1};
        {
            v8s Ah = pack8(*(const v4s*)(xrh), *(const v4s*)(xrh + 16));
            v8s Al = pack8(*(const v4s*)(xrl), *(const v4s*)(xrl + 16));
            oacc0 = MFMA(Ah, POh0, oacc0, 0, 0, 0);
            oacc0 = MFMA(Ah, POl0, oacc0, 0, 0, 0);
            oacc0 = MFMA(Al, POh0, oacc0, 0, 0, 0);
            oacc1 = MFMA(Ah, POh1, oacc1, 0, 0, 0);
            oacc1 = MFMA(Ah, POl1, oacc1, 0, 0, 0);
            oacc1 = MFMA(Al, POh1, oacc1, 0, 0, 0);
        }
        for (int ks = 1; ks < 16; ++ks) {
            int k0 = ks * 32;
            v8s Ah = pack8(*(const v4s*)(xrh + k0), *(const v4s*)(xrh + k0 + 16));
            v8s Al = pack8(*(const v4s*)(xrl + k0), *(const v4s*)(xrl + k0 + 16));
            const unsigned short* wb0 = pkO + (ks * 2 + 0) * 8192 + wv * 512 + lane * 8;
            const unsigned short* wb1 = pkO + (ks * 2 + 1) * 8192 + wv * 512 + lane * 8;
            v8s Bh0 = *(const v8s*)(wb0);
            v8s Bl0 = *(const v8s*)(wb0 + 4096);
            v8s Bh1 = *(const v8s*)(wb1);
            v8s Bl1 = *(const v8s*)(wb1 + 4096);
            oacc0 = MFMA(Ah, Bh0, oacc0, 0, 0, 0);
            oacc0 = MFMA(Ah, Bl0, oacc0, 0, 0, 0);
            oacc0 = MFMA(Al, Bh0, oacc0, 0, 0, 0);
            oacc1 = MFMA(Ah, Bh1, oacc1, 0, 0, 0);
            oacc1 = MFMA(Ah, Bl1, oacc1, 0, 0, 0);
            oacc1 = MFMA(Al, Bh1, oacc1, 0, 0, 0);
        }
        float pr[4] = {0.f, 0.f, 0.f, 0.f};
#pragma unroll
        for (int r = 0; r < 4; ++r) {
            pr[r] += lrelu(oacc0[r]) * ow2_lds[col0];
            pr[r] += lrelu(oacc1[r]) * ow2_lds[128 + col0];
        }
#pragma unroll
        for (int off = 1; off < 16; off <<= 1) {
#pragma unroll
            for (int r = 0; r < 4; ++r) pr[r] += __shfl_xor(pr[r], off);
        }
        if (lr == 0) {
#pragma unroll
            for (int r = 0; r < 4; ++r) red_lds[lg * 4 + r][wv] = pr[r];
        }
        __syncthreads();
        if (tid < TN) {
            float s = 0.f;
#pragma unroll
            for (int w = 0; w < 8; w++) s += red_lds[tid][w];
            out[node0 + tid] = s + o_b2[0];
        }
    }
}

extern "C" void kernel_launch(void* const* d_in, const int* in_sizes, int n_in,
                              void* d_out, int out_size, void* d_ws, size_t ws_size,
                              hipStream_t stream)
{
    const float* delay    = (const float*)d_in[0];
    const float* feat     = (const float*)d_in[1];
    const float* bitpos   = (const float*)d_in[2];
    const float* pofeat   = (const float*)d_in[3];
    const int*   srcidx   = (const int*)  d_in[4];
    const float* pi_w1    = (const float*)d_in[5];
    const float* pi_b1    = (const float*)d_in[6];
    const float* pi_w2    = (const float*)d_in[7];
    const float* pi_b2    = (const float*)d_in[8];
    const float* gate_w1  = (const float*)d_in[9];
    const float* gate_b1  = (const float*)d_in[10];
    const float* gate_w2  = (const float*)d_in[11];
    const float* gate_b2  = (const float*)d_in[12];
    const float* mod_w1   = (const float*)d_in[13];
    const float* mod_b1   = (const float*)d_in[14];
    const float* mod_w2   = (const float*)d_in[15];
    const float* mod_b2   = (const float*)d_in[16];
    const float* type_w1  = (const float*)d_in[17];
    const float* type_b1  = (const float*)d_in[18];
    const float* type_w2  = (const float*)d_in[19];
    const float* type_b2  = (const float*)d_in[20];
    const float* pos_w1   = (const float*)d_in[21];
    const float* pos_b1   = (const float*)d_in[22];
    const float* pos_w2   = (const float*)d_in[23];
    const float* pos_b2   = (const float*)d_in[24];
    const float* attn_vec = (const float*)d_in[25];
    const float* glob_w1  = (const float*)d_in[26];
    const float* glob_b1  = (const float*)d_in[27];
    const float* glob_w2  = (const float*)d_in[28];
    const float* glob_b2  = (const float*)d_in[29];
    const float* out_w1   = (const float*)d_in[30];
    const float* out_b1   = (const float*)d_in[31];
    const float* out_w2   = (const float*)d_in[32];
    const float* out_b2   = (const float*)d_in[33];

    float* buf0 = (float*)d_ws;
    float* buf1 = buf0 + (size_t)NP * HD;
    float* sd0  = buf1 + (size_t)NP * HD;
    float* sd1  = sd0 + NP;

    prep_kernel<<<1184, 256, 0, stream>>>(gate_w1, mod_w1, gate_w2, mod_w2, glob_w2, out_w1);

    pi_kernel<<<NP / TN, 256, 0, stream>>>(delay, pi_w1, pi_b1, pi_w2, pi_b2,
                                           attn_vec, buf0, sd0);

    for (int l = 0; l < NLVL; l++) {
        float* pv = (l & 1) ? buf1 : buf0;
        float* nx = (l & 1) ? buf0 : buf1;
        float* sp = (l & 1) ? sd1 : sd0;
        float* sn = (l & 1) ? sd0 : sd1;
        level_kernel<<<NP / TN, 512, 0, stream>>>(
            pv, nx, sp, sn, feat, bitpos, srcidx,
            gate_w1, gate_b1, gate_b2,
            mod_w1, mod_b1, mod_b2,
            type_w1, type_b1, type_w2, type_b2,
            pos_w1, pos_b1, pos_w2, pos_b2,
            attn_vec, l, (l != NLVL - 1) ? 1 : 0);
    }

    final_kernel<<<NP / TN, 512, 0, stream>>>(
        buf1, pofeat,
        glob_w1, glob_b1, glob_b2,
        out_b1, out_w2, out_b2,
        (float*)d_out);
}